// Round 2
// baseline (240.190 us; speedup 1.0000x reference)
//
#include <hip/hip_runtime.h>

#define NATOMS 13
#define NP (NATOMS * NATOMS)   // 169

constexpr int N_ = 1024;   // rows
constexpr int H_ = 512;    // inner dim
constexpr int O_ = 512;    // output dim
constexpr int HH = 256;    // h-tile (H_/2)
constexpr int OC = 256;    // o-tile (O_/2)
constexpr int NR = 16;     // max rows per pass (register accumulators)
constexpr int FPAD = 20;   // fp_s row stride (floats): 80B, 16B-aligned, odd-ish banks

// ---------------------------------------------------------------- bucket build
__global__ void build_buckets(const int* __restrict__ x,
                              const int* __restrict__ fact,
                              int* __restrict__ bstart,   // [NP+1]
                              int* __restrict__ brows,    // [N]
                              int N) {
    __shared__ int s_ids[N_];
    __shared__ int s_cnt[NP];
    __shared__ int s_start[NP + 1];
    const int tid = threadIdx.x, bd = blockDim.x;

    for (int i = tid; i < NP; i += bd) s_cnt[i] = 0;
    __syncthreads();
    for (int n = tid; n < N; n += bd) {
        const int f0 = fact[2 * n];
        const int id = x[f0 * 3 + 1] * NATOMS + x[f0 * 3 + 2];
        s_ids[n] = id;
        atomicAdd(&s_cnt[id], 1);
    }
    __syncthreads();
    if (tid == 0) {
        int run = 0;
        for (int i = 0; i < NP; ++i) { s_start[i] = run; run += s_cnt[i]; }
        s_start[NP] = run;
    }
    __syncthreads();
    for (int i = tid; i < NP; i += bd) s_cnt[i] = 0;
    __syncthreads();
    for (int n = tid; n < N; n += bd) {
        const int id = s_ids[n];
        const int pos = atomicAdd(&s_cnt[id], 1);
        brows[s_start[id] + pos] = n;
    }
    for (int i = tid; i <= NP; i += bd) bstart[i] = s_start[i];
}

// ---------------------------------------------------------------- grouped GEMV
// grid = NP * 4  (id  x  2 o-tiles  x  2 h-tiles), block = 128 threads.
// Each block streams W[g][h0:h0+HH, o0:o0+OC] ONCE and accumulates partial
// dot products for up to NR bucket rows simultaneously in registers.
__global__ __launch_bounds__(128)
void bucket_gemv(const int* __restrict__ bstart,
                 const int* __restrict__ brows,
                 const float* __restrict__ inp,
                 const float* __restrict__ params,
                 const float* __restrict__ bias,
                 const int* __restrict__ msg_to_p,
                 const int* __restrict__ order_p,
                 float* __restrict__ out,
                 int N) {
    const int g  = blockIdx.x >> 2;
    const int ot = blockIdx.x & 1;
    const int ht = (blockIdx.x >> 1) & 1;

    const int s0 = bstart[g];
    const int C  = bstart[g + 1] - s0;
    if (C == 0) return;

    const int msg_to = *msg_to_p;
    const int order  = *order_p;
    const int tid = threadIdx.x;
    const int h0 = ht * HH;
    const int o0 = ot * OC;

    __shared__ float fp_s[HH][FPAD];   // [h][r], r in [0,16)
    __shared__ int   s_rows[NR];

    const float* __restrict__ W = params + (size_t)g * H_ * O_;
    const float2 bv = *(const float2*)(bias + (size_t)g * O_ + o0 + 2 * tid);

    for (int base = 0; base < C; base += NR) {
        const int R = min(NR, C - base);
        if (tid < NR) s_rows[tid] = (tid < R) ? brows[s0 + base + tid] : 0;
        __syncthreads();

        // stage fact_prod slices: fp_s[h][r]
        for (int r = 0; r < NR; ++r) {
            if (r < R) {
                const int row = s_rows[r];
                for (int k = 0; k < HH; k += 128) {
                    const int h = k + tid;
                    float p = 1.0f;
                    for (int i = 0; i < order; ++i)
                        if (i != msg_to)
                            p *= inp[((size_t)i * N + row) * H_ + h0 + h];
                    fp_s[h][r] = p;
                }
            } else {
                for (int k = 0; k < HH; k += 128) fp_s[k + tid][r] = 0.0f;
            }
        }
        __syncthreads();

        float2 acc[NR];
#pragma unroll
        for (int r = 0; r < NR; ++r) acc[r] = make_float2(0.f, 0.f);

        const float* wp = W + (size_t)h0 * O_ + o0 + 2 * tid;

#define STEP4(fv, r0)                                        \
        acc[(r0)+0].x += (fv).x * w.x; acc[(r0)+0].y += (fv).x * w.y; \
        acc[(r0)+1].x += (fv).y * w.x; acc[(r0)+1].y += (fv).y * w.y; \
        acc[(r0)+2].x += (fv).z * w.x; acc[(r0)+2].y += (fv).z * w.y; \
        acc[(r0)+3].x += (fv).w * w.x; acc[(r0)+3].y += (fv).w * w.y;

#pragma unroll 4
        for (int h = 0; h < HH; ++h) {
            const float2 w = *(const float2*)wp;  wp += O_;
            const float4 f0 = *(const float4*)&fp_s[h][0];
            const float4 f1 = *(const float4*)&fp_s[h][4];
            const float4 f2 = *(const float4*)&fp_s[h][8];
            const float4 f3 = *(const float4*)&fp_s[h][12];
            STEP4(f0, 0)
            STEP4(f1, 4)
            STEP4(f2, 8)
            STEP4(f3, 12)
        }
#undef STEP4

#pragma unroll
        for (int r = 0; r < NR; ++r) {
            if (r < R) {
                const int row = s_rows[r];
                float ax = acc[r].x, ay = acc[r].y;
                if (ht == 0) { ax += bv.x; ay += bv.y; }  // bias exactly once
                float* op = out + (size_t)row * O_ + o0 + 2 * tid;
                atomicAdd(op,     ax);
                atomicAdd(op + 1, ay);
            }
        }
        __syncthreads();   // protect fp_s/s_rows before next pass
    }
}

// ---------------------------------------------------------------------- launch
extern "C" void kernel_launch(void* const* d_in, const int* in_sizes, int n_in,
                              void* d_out, int out_size, void* d_ws, size_t ws_size,
                              hipStream_t stream) {
    const int*   x      = (const int*)d_in[0];
    const int*   fact   = (const int*)d_in[1];
    const float* inp    = (const float*)d_in[2];
    const float* params = (const float*)d_in[3];
    const float* bias   = (const float*)d_in[4];
    const int*   msg_to = (const int*)d_in[5];
    const int*   order  = (const int*)d_in[6];
    float*       out    = (float*)d_out;

    const int N = in_sizes[1] / 2;   // 1024

    int* bstart = (int*)d_ws;            // NP+1
    int* brows  = bstart + (NP + 1);     // N

    hipMemsetAsync(d_out, 0, (size_t)N * O_ * sizeof(float), stream);

    hipLaunchKernelGGL(build_buckets, dim3(1), dim3(256), 0, stream,
                       x, fact, bstart, brows, N);

    hipLaunchKernelGGL(bucket_gemv, dim3(NP * 4), dim3(128), 0, stream,
                       bstart, brows, inp, params, bias, msg_to, order, out, N);
}

// Round 3
// 59.198 us; speedup vs baseline: 4.0574x; 4.0574x over previous
//
#include <hip/hip_runtime.h>

#define NATOMS 13
#define NP (NATOMS * NATOMS)   // 169

constexpr int N_ = 1024;               // rows
constexpr int H_ = 512;                // inner dim
constexpr int O_ = 512;                // output dim
constexpr int MAXPAIRS = (N_ + NP + 1) / 2;   // 597 upper bound on pair count
constexpr int HSPLIT = 2;
constexpr int HH = H_ / HSPLIT;        // 256
constexpr int NB = MAXPAIRS * HSPLIT;  // 1194 blocks

// ws layout (ints): [0] npairs; [8..) pr0[MAXPAIRS]; then pr1; then pid
// ------------------------------------------------------------- build pair list
__global__ void build_pairs(const int* __restrict__ x,
                            const int* __restrict__ fact,
                            int* __restrict__ ws, int N) {
    __shared__ int s_id[N_];
    __shared__ int s_cnt[NP];
    __shared__ int s_start[NP];
    __shared__ int s_pstart[NP];
    __shared__ int s_pos[NP];
    __shared__ int s_sorted[N_];
    const int tid = threadIdx.x, bd = blockDim.x;

    for (int i = tid; i < NP; i += bd) { s_cnt[i] = 0; s_pos[i] = 0; }
    __syncthreads();
    for (int n = tid; n < N; n += bd) {
        const int f0 = fact[2 * n];
        const int id = x[f0 * 3 + 1] * NATOMS + x[f0 * 3 + 2];
        s_id[n] = id;
        atomicAdd(&s_cnt[id], 1);
    }
    __syncthreads();
    if (tid == 0) {
        int run = 0, prun = 0;
        for (int g = 0; g < NP; ++g) {
            s_start[g] = run;   run  += s_cnt[g];
            s_pstart[g] = prun; prun += (s_cnt[g] + 1) >> 1;
        }
        ws[0] = prun;  // npairs
    }
    __syncthreads();
    for (int n = tid; n < N; n += bd) {
        const int id = s_id[n];
        const int p = atomicAdd(&s_pos[id], 1);
        s_sorted[s_start[id] + p] = n;
    }
    __syncthreads();
    int* pr0 = ws + 8;
    int* pr1 = ws + 8 + MAXPAIRS;
    int* pid = ws + 8 + 2 * MAXPAIRS;
    for (int g = tid; g < NP; g += bd) {
        const int c = s_cnt[g], st = s_start[g], ps = s_pstart[g];
        for (int k = 0; k < c; k += 2) {
            const int w = ps + (k >> 1);
            pr0[w] = s_sorted[st + k];
            pr1[w] = (k + 1 < c) ? s_sorted[st + k + 1] : -1;
            pid[w] = g;
        }
    }
}

// ------------------------------------------------------------------ pair GEMV
// One block per (pair, h-half). Streams W[id][h0:h0+256, :] once with float4
// loads (16B/lane) and applies it to BOTH rows of the pair (8 FMA / 16B).
// Partial results combined via atomicAdd into zeroed out.
__global__ __launch_bounds__(128)
void pair_gemv(const int* __restrict__ ws,
               const float* __restrict__ inp,
               const float* __restrict__ params,
               const float* __restrict__ bias,
               const int* __restrict__ msg_to_p,
               const int* __restrict__ order_p,
               float* __restrict__ out, int N) {
    // bijective XCD-chunked swizzle: consecutive logical blocks (same pair /
    // neighboring pairs, same W) land on the same XCD for L2 reuse.
    constexpr int q = NB / 8, r = NB % 8;
    const int b = blockIdx.x;
    const int xcd = b & 7, ii = b >> 3;
    const int Lg = (xcd < r ? xcd * (q + 1) : r * (q + 1) + (xcd - r) * q) + ii;
    const int pair = Lg >> 1;
    const int ht   = Lg & 1;

    const int npairs = ws[0];
    if (pair >= npairs) return;

    const int row0 = ws[8 + pair];
    const int row1 = ws[8 + MAXPAIRS + pair];
    const int id   = ws[8 + 2 * MAXPAIRS + pair];

    const int msg_to = *msg_to_p;
    const int order  = *order_p;
    const int tid = threadIdx.x;
    const int h0 = ht * HH;

    __shared__ float fp0[HH];
    __shared__ float fp1[HH];
    for (int h = tid; h < HH; h += 128) {
        float p0 = 1.0f, p1 = 1.0f;
        for (int i = 0; i < order; ++i) {
            if (i != msg_to) {
                p0 *= inp[((size_t)i * N + row0) * H_ + h0 + h];
                if (row1 >= 0)
                    p1 *= inp[((size_t)i * N + row1) * H_ + h0 + h];
            }
        }
        fp0[h] = p0;
        fp1[h] = (row1 >= 0) ? p1 : 0.0f;
    }
    __syncthreads();

    const float* __restrict__ wp =
        params + (size_t)id * H_ * O_ + (size_t)h0 * O_ + 4 * tid;

    float4 a0 = make_float4(0.f, 0.f, 0.f, 0.f);
    float4 a1 = make_float4(0.f, 0.f, 0.f, 0.f);
#pragma unroll 8
    for (int h = 0; h < HH; ++h) {
        const float4 w = *(const float4*)(wp + (size_t)h * O_);
        const float s0 = fp0[h];
        const float s1 = fp1[h];
        a0.x += s0 * w.x; a0.y += s0 * w.y; a0.z += s0 * w.z; a0.w += s0 * w.w;
        a1.x += s1 * w.x; a1.y += s1 * w.y; a1.z += s1 * w.z; a1.w += s1 * w.w;
    }

    if (ht == 0) {   // fold bias in exactly once per row
        const float4 bv = *(const float4*)(bias + (size_t)id * O_ + 4 * tid);
        a0.x += bv.x; a0.y += bv.y; a0.z += bv.z; a0.w += bv.w;
        a1.x += bv.x; a1.y += bv.y; a1.z += bv.z; a1.w += bv.w;
    }

    float* o0 = out + (size_t)row0 * O_ + 4 * tid;
    atomicAdd(o0 + 0, a0.x); atomicAdd(o0 + 1, a0.y);
    atomicAdd(o0 + 2, a0.z); atomicAdd(o0 + 3, a0.w);
    if (row1 >= 0) {
        float* o1 = out + (size_t)row1 * O_ + 4 * tid;
        atomicAdd(o1 + 0, a1.x); atomicAdd(o1 + 1, a1.y);
        atomicAdd(o1 + 2, a1.z); atomicAdd(o1 + 3, a1.w);
    }
}

// ---------------------------------------------------------------------- launch
extern "C" void kernel_launch(void* const* d_in, const int* in_sizes, int n_in,
                              void* d_out, int out_size, void* d_ws, size_t ws_size,
                              hipStream_t stream) {
    const int*   x      = (const int*)d_in[0];
    const int*   fact   = (const int*)d_in[1];
    const float* inp    = (const float*)d_in[2];
    const float* params = (const float*)d_in[3];
    const float* bias   = (const float*)d_in[4];
    const int*   msg_to = (const int*)d_in[5];
    const int*   order  = (const int*)d_in[6];
    float*       out    = (float*)d_out;

    const int N = in_sizes[1] / 2;   // 1024
    int* ws = (int*)d_ws;

    hipMemsetAsync(d_out, 0, (size_t)N * O_ * sizeof(float), stream);

    hipLaunchKernelGGL(build_pairs, dim3(1), dim3(256), 0, stream,
                       x, fact, ws, N);

    hipLaunchKernelGGL(pair_gemv, dim3(NB), dim3(128), 0, stream,
                       ws, inp, params, bias, msg_to, order, out, N);
}